// Round 4
// baseline (974.165 us; speedup 1.0000x reference)
//
#include <hip/hip_runtime.h>
#include <cstdint>

typedef __attribute__((ext_vector_type(8))) __bf16 bf16x8;
typedef __attribute__((ext_vector_type(4))) float f32x4;
typedef __attribute__((ext_vector_type(8))) unsigned short u16x8;
typedef __attribute__((ext_vector_type(4))) unsigned short u16x4;

__device__ __forceinline__ unsigned short f2bf(float f) {
    union { float f; unsigned u; } v; v.f = f;
    unsigned u = v.u;
    return (unsigned short)((u + 0x7FFFu + ((u >> 16) & 1u)) >> 16);
}

__device__ __forceinline__ void gload_lds16(const void* g, void* l) {
    auto gp = reinterpret_cast<__attribute__((address_space(1))) unsigned*>(
        reinterpret_cast<uintptr_t>(g));
    auto lp = reinterpret_cast<__attribute__((address_space(3))) unsigned*>(
        reinterpret_cast<uintptr_t>(l));
    __builtin_amdgcn_global_load_lds(gp, lp, 16, 0, 0);
}

// ---------------- fp32 -> bf16 cast ----------------
__global__ __launch_bounds__(256) void cvt_kernel(const float* __restrict__ in,
                                                  unsigned short* __restrict__ out, int n4) {
    int idx = blockIdx.x * 256 + threadIdx.x;
    int stride = gridDim.x * 256;
    for (int i = idx; i < n4; i += stride) {
        float4 v = ((const float4*)in)[i];
        u16x4 o;
        o.x = f2bf(v.x); o.y = f2bf(v.y); o.z = f2bf(v.z); o.w = f2bf(v.w);
        ((u16x4*)out)[i] = o;
    }
}

// ---------------- fp32 [R][C] -> bf16 [C][R] ----------------
__global__ __launch_bounds__(256) void transpose_cvt(const float* __restrict__ in,
                                                     unsigned short* __restrict__ out,
                                                     int R, int C) {
    __shared__ float t[32][33];
    int c0 = blockIdx.x * 32, r0 = blockIdx.y * 32;
    int tx = threadIdx.x, ty = threadIdx.y;
    for (int i = ty; i < 32; i += 8)
        t[i][tx] = in[(size_t)(r0 + i) * C + c0 + tx];
    __syncthreads();
    for (int i = ty; i < 32; i += 8)
        out[(size_t)(c0 + i) * R + r0 + tx] = f2bf(t[tx][i]);
}

// ---------------- pipelined 128x128 bf16 GEMM (triple-buffer, counted vmcnt) ----
// C[M][N] = A[M][K] @ Bt[N][K]^T. N%128==0, K%32==0, K>=96. M arbitrary (row-clamped).
__global__ __launch_bounds__(256) void gemm128p(const unsigned short* __restrict__ A,
                                                const unsigned short* __restrict__ Bt,
                                                void* __restrict__ C,
                                                const float* __restrict__ bias,
                                                int M, int N, int K, float scale, int split,
                                                int c_f32) {
    __shared__ unsigned short lds[3][2][4096];  // 48 KiB
    int ntx = N >> 7;
    int nwg = gridDim.x, bid = blockIdx.x, swz = bid;
    if ((nwg & 7) == 0) { int cpx = nwg >> 3; swz = (bid & 7) * cpx + (bid >> 3); }
    int m0 = (swz / ntx) << 7, n0 = (swz % ntx) << 7;
    int tid = threadIdx.x, lane = tid & 63, w = tid >> 6;
    int wm = w >> 1, wn = w & 1;
    int lr = lane & 15, lg = lane >> 4;
    int gq = lg ^ ((lr >> 1) & 3);
    int nkt = K >> 5;

    int arow = tid >> 2;
    int sgl = (tid & 3) ^ ((arow >> 1) & 3);
    int ra0 = m0 + arow;      if (ra0 > M - 1) ra0 = M - 1;
    int ra1 = m0 + 64 + arow; if (ra1 > M - 1) ra1 = M - 1;
    const unsigned short* a0 = A + (size_t)ra0 * K + (sgl << 3);
    const unsigned short* a1 = A + (size_t)ra1 * K + (sgl << 3);
    const unsigned short* b0 = Bt + (size_t)(n0 + arow) * K + (sgl << 3);
    const unsigned short* b1 = Bt + (size_t)(n0 + 64 + arow) * K + (sgl << 3);

    f32x4 acc[4][4] = {};

#define ST_A128(bi, kt) do { \
        gload_lds16(a0 + ((kt) << 5), &lds[bi][0][w << 9]); \
        gload_lds16(a1 + ((kt) << 5), &lds[bi][0][2048 + (w << 9)]); } while (0)
#define ST_B128(bi, kt) do { \
        gload_lds16(b0 + ((kt) << 5), &lds[bi][1][w << 9]); \
        gload_lds16(b1 + ((kt) << 5), &lds[bi][1][2048 + (w << 9)]); } while (0)

    ST_A128(0, 0); ST_B128(0, 0);
    ST_A128(1, 1); ST_B128(1, 1);

    int buf = 0;
    for (int t = 0; t < nkt; ++t) {
        asm volatile("s_waitcnt vmcnt(4)" ::: "memory");
        __builtin_amdgcn_s_barrier();
        int st = t + 2; if (st >= nkt) st = nkt - 1;
        int sbuf = buf + 2; if (sbuf >= 3) sbuf -= 3;
        ST_A128(sbuf, st);
        ST_B128(sbuf, st);
        const unsigned short* pa = &lds[buf][0][((wm << 6) + lr) * 32 + (gq << 3)];
        const unsigned short* pb = &lds[buf][1][((wn << 6) + lr) * 32 + (gq << 3)];
        bf16x8 af[4], bfr[4];
#pragma unroll
        for (int nt = 0; nt < 4; nt++) bfr[nt] = *(const bf16x8*)(pb + nt * 512);
#pragma unroll
        for (int mt = 0; mt < 4; mt++) af[mt] = *(const bf16x8*)(pa + mt * 512);
        __builtin_amdgcn_s_setprio(1);
#pragma unroll
        for (int mt = 0; mt < 4; mt++)
#pragma unroll
            for (int nt = 0; nt < 4; nt++)
                acc[mt][nt] = __builtin_amdgcn_mfma_f32_16x16x32_bf16(af[mt], bfr[nt], acc[mt][nt], 0, 0, 0);
        __builtin_amdgcn_s_setprio(0);
        buf++; if (buf == 3) buf = 0;
    }
#undef ST_A128
#undef ST_B128

#pragma unroll
    for (int mt = 0; mt < 4; mt++) {
#pragma unroll
        for (int nt = 0; nt < 4; nt++) {
            int col = n0 + (wn << 6) + (nt << 4) + lr;
            float sc = (col < split) ? scale : 1.0f;
            float bv = bias ? bias[col] : 0.0f;
#pragma unroll
            for (int r = 0; r < 4; r++) {
                int row = m0 + (wm << 6) + (mt << 4) + (lg << 2) + r;
                if (row < M) {
                    float v = acc[mt][nt][r] * sc + bv;
                    if (c_f32) ((float*)C)[(size_t)row * N + col] = v;
                    else       ((unsigned short*)C)[(size_t)row * N + col] = f2bf(v);
                }
            }
        }
    }
}

// ---------------- large bf16 GEMM: 512x256 block tile ----------------
// 8 waves (4m x 2n), per-wave 128x128 output (acc[8][8] f32x4 = 256 AGPR).
// Triple-buffered LDS (3 x 48 KiB = 144 KiB), counted vmcnt(6), 1 barrier / K-tile.
// Per K-tile (BK=32): 64 MFMA, 12 ds_read_b128, 6 gload_lds, 1 vmcnt, 1 barrier.
// Requires M%512==0, N%256==0, K%32==0, K>=96.
__global__ __launch_bounds__(512, 2) void gemm512(const unsigned short* __restrict__ A,
                                                  const unsigned short* __restrict__ Bt,
                                                  unsigned short* __restrict__ C,
                                                  int M, int N, int K) {
    __shared__ unsigned short lds[3][24576];  // [buf][A:16384 | B:8192] elems
    int nkt = K >> 5;
    int ntx = N >> 8;
    int nwg = gridDim.x, bid = blockIdx.x, swz = bid;
    if ((nwg & 7) == 0) { int cpx = nwg >> 3; swz = (bid & 7) * cpx + (bid >> 3); }
    int m0 = (swz / ntx) << 9, n0 = (swz % ntx) << 8;
    int tid = threadIdx.x, lane = tid & 63, w = tid >> 6;
    int wm = w >> 1, wn = w & 1;
    int lr = lane & 15, lg = lane >> 4;
    int gq = lg ^ ((lr >> 1) & 3);

    // staging: round j covers plane rows [128j, 128j+128); thread -> row 128j+(tid>>2),
    // phys granule tid&3, inverse-swizzled global granule sgl.
    int srow = tid >> 2;
    int sgl = (tid & 3) ^ ((srow >> 1) & 3);
    const unsigned short* aP = A + (size_t)(m0 + srow) * K + (sgl << 3);
    const unsigned short* bP = Bt + (size_t)(n0 + srow) * K + (sgl << 3);
    size_t aStep = (size_t)128 * K;

    f32x4 acc[8][8] = {};

    // per-tile load order (6): A0 A1 A2 | A3 B0 B1
#define ST_P1(bi, kt) do { \
        gload_lds16(aP + ((kt) << 5),             &lds[bi][(w << 9)]); \
        gload_lds16(aP + aStep + ((kt) << 5),     &lds[bi][4096 + (w << 9)]); \
        gload_lds16(aP + 2 * aStep + ((kt) << 5), &lds[bi][8192 + (w << 9)]); } while (0)
#define ST_P2(bi, kt) do { \
        gload_lds16(aP + 3 * aStep + ((kt) << 5), &lds[bi][12288 + (w << 9)]); \
        gload_lds16(bP + ((kt) << 5),             &lds[bi][16384 + (w << 9)]); \
        gload_lds16(bP + aStep + ((kt) << 5),     &lds[bi][20480 + (w << 9)]); } while (0)

    ST_P1(0, 0); ST_P2(0, 0);
    ST_P1(1, 1); ST_P2(1, 1);

    int buf = 0;
    for (int t = 0; t < nkt; ++t) {
        asm volatile("s_waitcnt vmcnt(6)" ::: "memory");
        __builtin_amdgcn_s_barrier();
        int st = t + 2; if (st >= nkt) st = nkt - 1;
        int sbuf = buf + 2; if (sbuf >= 3) sbuf -= 3;

        const unsigned short* pa = &lds[buf][((wm << 7) + lr) * 32 + (gq << 3)];
        const unsigned short* pb = &lds[buf][16384 + ((wn << 7) + lr) * 32 + (gq << 3)];

        // phase 1: stage 3 loads; read all A-frags + B n-half 0; 32 MFMA
        ST_P1(sbuf, st);
        bf16x8 af[8], bfr[4];
#pragma unroll
        for (int mt = 0; mt < 8; mt++) af[mt] = *(const bf16x8*)(pa + mt * 512);
#pragma unroll
        for (int nt = 0; nt < 4; nt++) bfr[nt] = *(const bf16x8*)(pb + nt * 512);
        __builtin_amdgcn_s_setprio(1);
#pragma unroll
        for (int mt = 0; mt < 8; mt++)
#pragma unroll
            for (int nt = 0; nt < 4; nt++)
                acc[mt][nt] = __builtin_amdgcn_mfma_f32_16x16x32_bf16(af[mt], bfr[nt], acc[mt][nt], 0, 0, 0);
        __builtin_amdgcn_s_setprio(0);

        // phase 2: stage 3 loads; read B n-half 1 (reuse A-frags); 32 MFMA
        ST_P2(sbuf, st);
#pragma unroll
        for (int nt = 0; nt < 4; nt++) bfr[nt] = *(const bf16x8*)(pb + (nt + 4) * 512);
        __builtin_amdgcn_s_setprio(1);
#pragma unroll
        for (int mt = 0; mt < 8; mt++)
#pragma unroll
            for (int nt = 0; nt < 4; nt++)
                acc[mt][nt + 4] = __builtin_amdgcn_mfma_f32_16x16x32_bf16(af[mt], bfr[nt], acc[mt][nt + 4], 0, 0, 0);
        __builtin_amdgcn_s_setprio(0);

        buf++; if (buf == 3) buf = 0;
    }
#undef ST_P1
#undef ST_P2

#pragma unroll
    for (int mt = 0; mt < 8; mt++) {
#pragma unroll
        for (int nt = 0; nt < 8; nt++) {
            int col = n0 + (wn << 7) + (nt << 4) + lr;
            size_t rbase = (size_t)(m0 + (wm << 7) + (mt << 4) + (lg << 2));
#pragma unroll
            for (int r = 0; r < 4; r++)
                C[(rbase + r) * N + col] = f2bf(acc[mt][nt][r]);
        }
    }
}

// ---------------- fused flash attention over 1088 keys (1024 media + 64 latent) ----------------
__global__ __launch_bounds__(256) void attn_kernel(const unsigned short* __restrict__ qg, int qstride,
                                                   const unsigned short* __restrict__ kvg,
                                                   const unsigned short* __restrict__ lkvg, int lstride,
                                                   unsigned short* __restrict__ og) {
    __shared__ unsigned short K_lds[64 * 72];
    __shared__ unsigned short V_lds[64 * 72];
    __shared__ unsigned short P_lds[4][16 * 72];
    int bm = blockIdx.x >> 4, h = blockIdx.x & 15;
    int tid = threadIdx.x, lane = tid & 63, w = tid >> 6;
    int lr = lane & 15, lg = lane >> 4;

    bf16x8 qf[2];
#pragma unroll
    for (int kk = 0; kk < 2; kk++)
        qf[kk] = *(const bf16x8*)(qg + (size_t)((w << 4) + lr) * qstride + (h << 6) + (kk << 5) + (lg << 3));

    f32x4 acc[4] = {};
    float m_run[4], l_run[4];
#pragma unroll
    for (int r = 0; r < 4; r++) { m_run[r] = -1e30f; l_run[r] = 0.0f; }

    int jrow = tid >> 2;
    int seg = (tid & 3) << 4;

    const unsigned short* s0 = kvg + (size_t)((bm << 10) + jrow) * 2048 + (h << 6);
    u16x8 k0 = *(const u16x8*)(s0 + seg);
    u16x8 k1 = *(const u16x8*)(s0 + seg + 8);
    u16x8 v0 = *(const u16x8*)(s0 + 1024 + seg);
    u16x8 v1 = *(const u16x8*)(s0 + 1024 + seg + 8);

    for (int t = 0; t < 17; t++) {
        *(u16x8*)(&K_lds[jrow * 72 + seg]) = k0;
        *(u16x8*)(&K_lds[jrow * 72 + seg + 8]) = k1;
#pragma unroll
        for (int c = 0; c < 8; c++) V_lds[(seg + c) * 72 + jrow] = v0[c];
#pragma unroll
        for (int c = 0; c < 8; c++) V_lds[(seg + 8 + c) * 72 + jrow] = v1[c];
        __syncthreads();

        u16x8 nk0 = k0, nk1 = k1, nv0 = v0, nv1 = v1;
        if (t < 16) {
            const unsigned short* src = (t < 15)
                ? kvg + (size_t)((bm << 10) + ((t + 1) << 6) + jrow) * 2048 + (h << 6)
                : lkvg + (size_t)jrow * lstride + (h << 6);
            nk0 = *(const u16x8*)(src + seg);
            nk1 = *(const u16x8*)(src + seg + 8);
            nv0 = *(const u16x8*)(src + 1024 + seg);
            nv1 = *(const u16x8*)(src + 1024 + seg + 8);
        }

        f32x4 s[4] = {};
#pragma unroll
        for (int jt = 0; jt < 4; jt++) {
#pragma unroll
            for (int kk = 0; kk < 2; kk++) {
                bf16x8 kf = *(const bf16x8*)(&K_lds[(size_t)((jt << 4) + lr) * 72 + (kk << 5) + (lg << 3)]);
                s[jt] = __builtin_amdgcn_mfma_f32_16x16x32_bf16(qf[kk], kf, s[jt], 0, 0, 0);
            }
        }
#pragma unroll
        for (int r = 0; r < 4; r++) {
            float mx = fmaxf(fmaxf(s[0][r], s[1][r]), fmaxf(s[2][r], s[3][r]));
            mx = fmaxf(mx, __shfl_xor(mx, 1));
            mx = fmaxf(mx, __shfl_xor(mx, 2));
            mx = fmaxf(mx, __shfl_xor(mx, 4));
            mx = fmaxf(mx, __shfl_xor(mx, 8));
            float nm = fmaxf(m_run[r], mx);
            float fct = __expf(m_run[r] - nm);
            m_run[r] = nm;
            float p0 = __expf(s[0][r] - nm);
            float p1 = __expf(s[1][r] - nm);
            float p2 = __expf(s[2][r] - nm);
            float p3 = __expf(s[3][r] - nm);
            float sum = p0 + p1 + p2 + p3;
            sum += __shfl_xor(sum, 1);
            sum += __shfl_xor(sum, 2);
            sum += __shfl_xor(sum, 4);
            sum += __shfl_xor(sum, 8);
            l_run[r] = l_run[r] * fct + sum;
#pragma unroll
            for (int dt = 0; dt < 4; dt++) acc[dt][r] *= fct;
            int prow = ((lg << 2) + r) * 72;
            P_lds[w][prow + lr]      = f2bf(p0);
            P_lds[w][prow + 16 + lr] = f2bf(p1);
            P_lds[w][prow + 32 + lr] = f2bf(p2);
            P_lds[w][prow + 48 + lr] = f2bf(p3);
        }
#pragma unroll
        for (int jkk = 0; jkk < 2; jkk++) {
            bf16x8 pf = *(const bf16x8*)(&P_lds[w][(size_t)lr * 72 + (jkk << 5) + (lg << 3)]);
#pragma unroll
            for (int dt = 0; dt < 4; dt++) {
                bf16x8 vf = *(const bf16x8*)(&V_lds[(size_t)((dt << 4) + lr) * 72 + (jkk << 5) + (lg << 3)]);
                acc[dt] = __builtin_amdgcn_mfma_f32_16x16x32_bf16(pf, vf, acc[dt], 0, 0, 0);
            }
        }
        __syncthreads();
        k0 = nk0; k1 = nk1; v0 = nv0; v1 = nv1;
    }
#pragma unroll
    for (int dt = 0; dt < 4; dt++) {
#pragma unroll
        for (int r = 0; r < 4; r++) {
            int i = (w << 4) + (lg << 2) + r;
            float v = acc[dt][r] / l_run[r];
            og[(size_t)((bm << 6) + i) * 1024 + (h << 6) + (dt << 4) + lr] = f2bf(v);
        }
    }
}

extern "C" void kernel_launch(void* const* d_in, const int* in_sizes, int n_in,
                              void* d_out, int out_size, void* d_ws, size_t ws_size,
                              hipStream_t stream) {
    const float* x       = (const float*)d_in[0];
    const float* latents = (const float*)d_in[1];
    const float* Wq      = (const float*)d_in[2];
    const float* Wkv     = (const float*)d_in[3];
    const float* Wout    = (const float*)d_in[4];
    const float* bout    = (const float*)d_in[5];
    char* ws = (char*)d_ws;
    unsigned short* xb    = (unsigned short*)(ws);                 // 64 MiB  [32768][1024]
    unsigned short* kvb   = (unsigned short*)(ws + 67108864);      // 128 MiB [32768][2048]
    unsigned short* wqkvt = (unsigned short*)(ws + 201326592);     // 6 MiB   [3072][1024] (Wq^T | Wkv^T)
    unsigned short* wkvt  = wqkvt + 1024 * 1024;                   //         rows 1024..3071
    unsigned short* woutt = (unsigned short*)(ws + 207618048);     // 2 MiB   [1024][1024]
    unsigned short* latb  = (unsigned short*)(ws + 209715200);     // 128 KiB [64][1024]
    unsigned short* qlkvb = (unsigned short*)(ws + 209846272);     // 384 KiB [64][3072] (q | lk | lv)
    unsigned short* attnb = (unsigned short*)(ws + 210239488);     // 4 MiB   [2048][1024]

    cvt_kernel<<<2048, 256, 0, stream>>>(x, xb, 33554432 / 4);
    cvt_kernel<<<64, 256, 0, stream>>>(latents, latb, 65536 / 4);
    dim3 tb(32, 8);
    transpose_cvt<<<dim3(32, 32), tb, 0, stream>>>(Wq, wqkvt, 1024, 1024);
    transpose_cvt<<<dim3(64, 32), tb, 0, stream>>>(Wkv, wkvt, 1024, 2048);
    transpose_cvt<<<dim3(32, 32), tb, 0, stream>>>(Wout, woutt, 1024, 1024);
    // [q | lkv] = latents @ [Wq | Wkv]; q-part (cols<1024) scaled by dh^-0.5
    gemm128p<<<24, 256, 0, stream>>>(latb, wqkvt, qlkvb, nullptr, 64, 3072, 1024, 0.125f, 1024, 0);
    // kv = x @ Wkv  (dominant GEMM): 512x256 tiles -> 64 x 8 = 512 blocks
    gemm512<<<512, 512, 0, stream>>>(xb, wkvt, kvb, 32768, 2048, 1024);
    // fused attention
    attn_kernel<<<512, 256, 0, stream>>>(qlkvb, 3072, kvb, qlkvb + 1024, 3072, attnb);
    // out = attnout @ Wout + bout (fp32 out)
    gemm128p<<<128, 256, 0, stream>>>(attnb, woutt, (void*)d_out, bout, 2048, 1024, 1024, 1.0f, 0, 1);
}

// Round 6
// 442.714 us; speedup vs baseline: 2.2004x; 2.2004x over previous
//
#include <hip/hip_runtime.h>
#include <cstdint>

typedef __attribute__((ext_vector_type(8))) __bf16 bf16x8;
typedef __attribute__((ext_vector_type(4))) float f32x4;
typedef __attribute__((ext_vector_type(8))) unsigned short u16x8;
typedef __attribute__((ext_vector_type(4))) unsigned short u16x4;

__device__ __forceinline__ unsigned short f2bf(float f) {
    union { float f; unsigned u; } v; v.f = f;
    unsigned u = v.u;
    return (unsigned short)((u + 0x7FFFu + ((u >> 16) & 1u)) >> 16);
}

__device__ __forceinline__ void gload_lds16(const void* g, void* l) {
    auto gp = reinterpret_cast<__attribute__((address_space(1))) unsigned*>(
        reinterpret_cast<uintptr_t>(g));
    auto lp = reinterpret_cast<__attribute__((address_space(3))) unsigned*>(
        reinterpret_cast<uintptr_t>(l));
    __builtin_amdgcn_global_load_lds(gp, lp, 16, 0, 0);
}

// ---------------- fp32 -> bf16 cast ----------------
__global__ __launch_bounds__(256) void cvt_kernel(const float* __restrict__ in,
                                                  unsigned short* __restrict__ out, int n4) {
    int idx = blockIdx.x * 256 + threadIdx.x;
    int stride = gridDim.x * 256;
    for (int i = idx; i < n4; i += stride) {
        float4 v = ((const float4*)in)[i];
        u16x4 o;
        o.x = f2bf(v.x); o.y = f2bf(v.y); o.z = f2bf(v.z); o.w = f2bf(v.w);
        ((u16x4*)out)[i] = o;
    }
}

// ---------------- fp32 [R][C] -> bf16 [C][R] ----------------
__global__ __launch_bounds__(256) void transpose_cvt(const float* __restrict__ in,
                                                     unsigned short* __restrict__ out,
                                                     int R, int C) {
    __shared__ float t[32][33];
    int c0 = blockIdx.x * 32, r0 = blockIdx.y * 32;
    int tx = threadIdx.x, ty = threadIdx.y;
    for (int i = ty; i < 32; i += 8)
        t[i][tx] = in[(size_t)(r0 + i) * C + c0 + tx];
    __syncthreads();
    for (int i = ty; i < 32; i += 8)
        out[(size_t)(c0 + i) * R + r0 + tx] = f2bf(t[tx][i]);
}

// ---------------- pipelined 128x128 bf16 GEMM (triple-buffer, counted vmcnt) ----
// Race-hardened seam: vmcnt(4)+lgkmcnt(0) + sched_barrier fences around s_barrier
// (rule #18: MFMA/lgkm waits must not sink past the barrier that precedes LDS overwrite).
__global__ __launch_bounds__(256) void gemm128p(const unsigned short* __restrict__ A,
                                                const unsigned short* __restrict__ Bt,
                                                void* __restrict__ C,
                                                const float* __restrict__ bias,
                                                int M, int N, int K, float scale, int split,
                                                int c_f32) {
    __shared__ unsigned short lds[3][2][4096];  // 48 KiB
    int ntx = N >> 7;
    int nwg = gridDim.x, bid = blockIdx.x, swz = bid;
    if ((nwg & 7) == 0) { int cpx = nwg >> 3; swz = (bid & 7) * cpx + (bid >> 3); }
    int m0 = (swz / ntx) << 7, n0 = (swz % ntx) << 7;
    int tid = threadIdx.x, lane = tid & 63, w = tid >> 6;
    int wm = w >> 1, wn = w & 1;
    int lr = lane & 15, lg = lane >> 4;
    int gq = lg ^ ((lr >> 1) & 3);
    int nkt = K >> 5;

    int arow = tid >> 2;
    int sgl = (tid & 3) ^ ((arow >> 1) & 3);
    int ra0 = m0 + arow;      if (ra0 > M - 1) ra0 = M - 1;
    int ra1 = m0 + 64 + arow; if (ra1 > M - 1) ra1 = M - 1;
    const unsigned short* a0 = A + (size_t)ra0 * K + (sgl << 3);
    const unsigned short* a1 = A + (size_t)ra1 * K + (sgl << 3);
    const unsigned short* b0 = Bt + (size_t)(n0 + arow) * K + (sgl << 3);
    const unsigned short* b1 = Bt + (size_t)(n0 + 64 + arow) * K + (sgl << 3);

    f32x4 acc[4][4] = {};

#define ST_A128(bi, kt) do { \
        gload_lds16(a0 + ((kt) << 5), &lds[bi][0][w << 9]); \
        gload_lds16(a1 + ((kt) << 5), &lds[bi][0][2048 + (w << 9)]); } while (0)
#define ST_B128(bi, kt) do { \
        gload_lds16(b0 + ((kt) << 5), &lds[bi][1][w << 9]); \
        gload_lds16(b1 + ((kt) << 5), &lds[bi][1][2048 + (w << 9)]); } while (0)

    ST_A128(0, 0); ST_B128(0, 0);
    ST_A128(1, 1); ST_B128(1, 1);

    int buf = 0;
    for (int t = 0; t < nkt; ++t) {
        asm volatile("s_waitcnt vmcnt(4) lgkmcnt(0)" ::: "memory");
        __builtin_amdgcn_sched_barrier(0);
        __builtin_amdgcn_s_barrier();
        __builtin_amdgcn_sched_barrier(0);
        int st = t + 2; if (st >= nkt) st = nkt - 1;
        int sbuf = buf + 2; if (sbuf >= 3) sbuf -= 3;
        ST_A128(sbuf, st);
        ST_B128(sbuf, st);
        const unsigned short* pa = &lds[buf][0][((wm << 6) + lr) * 32 + (gq << 3)];
        const unsigned short* pb = &lds[buf][1][((wn << 6) + lr) * 32 + (gq << 3)];
        bf16x8 af[4], bfr[4];
#pragma unroll
        for (int nt = 0; nt < 4; nt++) bfr[nt] = *(const bf16x8*)(pb + nt * 512);
#pragma unroll
        for (int mt = 0; mt < 4; mt++) af[mt] = *(const bf16x8*)(pa + mt * 512);
        __builtin_amdgcn_s_setprio(1);
#pragma unroll
        for (int mt = 0; mt < 4; mt++)
#pragma unroll
            for (int nt = 0; nt < 4; nt++)
                acc[mt][nt] = __builtin_amdgcn_mfma_f32_16x16x32_bf16(af[mt], bfr[nt], acc[mt][nt], 0, 0, 0);
        __builtin_amdgcn_s_setprio(0);
        buf++; if (buf == 3) buf = 0;
    }
#undef ST_A128
#undef ST_B128

#pragma unroll
    for (int mt = 0; mt < 4; mt++) {
#pragma unroll
        for (int nt = 0; nt < 4; nt++) {
            int col = n0 + (wn << 6) + (nt << 4) + lr;
            float sc = (col < split) ? scale : 1.0f;
            float bv = bias ? bias[col] : 0.0f;
#pragma unroll
            for (int r = 0; r < 4; r++) {
                int row = m0 + (wm << 6) + (mt << 4) + (lg << 2) + r;
                if (row < M) {
                    float v = acc[mt][nt][r] * sc + bv;
                    if (c_f32) ((float*)C)[(size_t)row * N + col] = v;
                    else       ((unsigned short*)C)[(size_t)row * N + col] = f2bf(v);
                }
            }
        }
    }
}

// ---------------- large bf16 GEMM: 256x256 tile, A direct-to-register ----------------
// A fragments load global->VGPR (4 n-waves share addresses -> L1-served); B stays in
// swizzled triple-buffered LDS via gload_lds. LDS traffic/iter: 128KB -> 48KB.
// 8 waves (2m x 4n), per-wave 128x64 (acc[8][4] f32x4 = 128 regs + areg 32 + bfr 16).
// VMEM order/iter: [LD_A(t+1) x8][ST_B(t+2) x2] -> vmcnt(2) at loop top drains A(t),B(t).
// Requires M%256==0, N%256==0, K%32==0, K>=96.
__global__ __launch_bounds__(512, 2) void gemm256(const unsigned short* __restrict__ A,
                                                  const unsigned short* __restrict__ Bt,
                                                  unsigned short* __restrict__ C,
                                                  int M, int N, int K) {
    __shared__ unsigned short ldsB[3][8192];  // 3 x [256][32] bf16 = 48 KiB
    int nkt = K >> 5;
    int ntx = N >> 8;
    int nwg = gridDim.x, bid = blockIdx.x, swz = bid;
    if ((nwg & 7) == 0) { int cpx = nwg >> 3; swz = (bid & 7) * cpx + (bid >> 3); }
    int m0 = (swz / ntx) << 8, n0 = (swz % ntx) << 8;
    int tid = threadIdx.x, lane = tid & 63, w = tid >> 6;
    int wm = w >> 2, wn = w & 3;
    int lr = lane & 15, lg = lane >> 4;
    int gq = lg ^ ((lr >> 1) & 3);

    // B staging: thread covers plane bytes tid*16 (+8192 for rows 128..255)
    int srow = tid >> 2;
    int sgl = (tid & 3) ^ ((srow >> 1) & 3);
    const unsigned short* b0 = Bt + (size_t)(n0 + srow) * K + (sgl << 3);
    const unsigned short* b1 = Bt + (size_t)(n0 + 128 + srow) * K + (sgl << 3);

    // A direct: wave wm's fragment rows, lane (lr,lg) -> row base + mt*16, k-granule lg
    const unsigned short* aBase = A + (size_t)(m0 + (wm << 7) + lr) * K + (lg << 3);
    size_t aRowStep = (size_t)16 * K;

    f32x4 acc[8][4] = {};
    bf16x8 areg[8];

#define ST_B(bi, kt) do { \
        gload_lds16(b0 + ((kt) << 5), &ldsB[bi][w << 9]); \
        gload_lds16(b1 + ((kt) << 5), &ldsB[bi][4096 + (w << 9)]); } while (0)
#define LD_A(mt_, kt) areg[mt_] = *(const bf16x8*)(aBase + (size_t)(mt_) * aRowStep + ((kt) << 5))

    // prologue: A(0) first (8 loads), then B stages (must be the 2-newest groups)
#pragma unroll
    for (int mt = 0; mt < 8; mt++) LD_A(mt, 0);
    __builtin_amdgcn_sched_barrier(0);
    ST_B(0, 0);
    ST_B(1, 1);

    int buf = 0;
    for (int t = 0; t < nkt; ++t) {
        asm volatile("s_waitcnt vmcnt(2) lgkmcnt(0)" ::: "memory");
        __builtin_amdgcn_sched_barrier(0);
        __builtin_amdgcn_s_barrier();
        __builtin_amdgcn_sched_barrier(0);
        int tn = t + 1; if (tn >= nkt) tn = nkt - 1;  // A prefetch tile (clamped: uniform count)
        int ts = t + 2; if (ts >= nkt) ts = nkt - 1;  // B stage tile
        int sbuf = buf + 2; if (sbuf >= 3) sbuf -= 3;

        const unsigned short* pb = &ldsB[buf][((wn << 6) + lr) * 32 + (gq << 3)];
        bf16x8 bfr[4];
#pragma unroll
        for (int nt = 0; nt < 4; nt++) bfr[nt] = *(const bf16x8*)(pb + nt * 512);

        // phase 1: MFMA m-rows 0..63 with areg[0..3](t), then refill areg[0..3] <- tile tn
        __builtin_amdgcn_s_setprio(1);
#pragma unroll
        for (int mt = 0; mt < 4; mt++)
#pragma unroll
            for (int nt = 0; nt < 4; nt++)
                acc[mt][nt] = __builtin_amdgcn_mfma_f32_16x16x32_bf16(areg[mt], bfr[nt], acc[mt][nt], 0, 0, 0);
        __builtin_amdgcn_s_setprio(0);
#pragma unroll
        for (int mt = 0; mt < 4; mt++) LD_A(mt, tn);

        // phase 2: MFMA m-rows 64..127, then refill areg[4..7]
        __builtin_amdgcn_s_setprio(1);
#pragma unroll
        for (int mt = 4; mt < 8; mt++)
#pragma unroll
            for (int nt = 0; nt < 4; nt++)
                acc[mt][nt] = __builtin_amdgcn_mfma_f32_16x16x32_bf16(areg[mt], bfr[nt], acc[mt][nt], 0, 0, 0);
        __builtin_amdgcn_s_setprio(0);
#pragma unroll
        for (int mt = 4; mt < 8; mt++) LD_A(mt, tn);
        __builtin_amdgcn_sched_barrier(0);   // pin: all A-loads issued before B-stages
        ST_B(sbuf, ts);

        buf++; if (buf == 3) buf = 0;
    }
#undef ST_B
#undef LD_A

#pragma unroll
    for (int mt = 0; mt < 8; mt++) {
#pragma unroll
        for (int nt = 0; nt < 4; nt++) {
            int col = n0 + (wn << 6) + (nt << 4) + lr;
            size_t rbase = (size_t)(m0 + (wm << 7) + (mt << 4) + (lg << 2));
#pragma unroll
            for (int r = 0; r < 4; r++)
                C[(rbase + r) * N + col] = f2bf(acc[mt][nt][r]);
        }
    }
}

// ---------------- fused flash attention over 1088 keys (1024 media + 64 latent) ----------------
__global__ __launch_bounds__(256) void attn_kernel(const unsigned short* __restrict__ qg, int qstride,
                                                   const unsigned short* __restrict__ kvg,
                                                   const unsigned short* __restrict__ lkvg, int lstride,
                                                   unsigned short* __restrict__ og) {
    __shared__ unsigned short K_lds[64 * 72];
    __shared__ unsigned short V_lds[64 * 72];
    __shared__ unsigned short P_lds[4][16 * 72];
    int bm = blockIdx.x >> 4, h = blockIdx.x & 15;
    int tid = threadIdx.x, lane = tid & 63, w = tid >> 6;
    int lr = lane & 15, lg = lane >> 4;

    bf16x8 qf[2];
#pragma unroll
    for (int kk = 0; kk < 2; kk++)
        qf[kk] = *(const bf16x8*)(qg + (size_t)((w << 4) + lr) * qstride + (h << 6) + (kk << 5) + (lg << 3));

    f32x4 acc[4] = {};
    float m_run[4], l_run[4];
#pragma unroll
    for (int r = 0; r < 4; r++) { m_run[r] = -1e30f; l_run[r] = 0.0f; }

    int jrow = tid >> 2;
    int seg = (tid & 3) << 4;

    const unsigned short* s0 = kvg + (size_t)((bm << 10) + jrow) * 2048 + (h << 6);
    u16x8 k0 = *(const u16x8*)(s0 + seg);
    u16x8 k1 = *(const u16x8*)(s0 + seg + 8);
    u16x8 v0 = *(const u16x8*)(s0 + 1024 + seg);
    u16x8 v1 = *(const u16x8*)(s0 + 1024 + seg + 8);

    for (int t = 0; t < 17; t++) {
        *(u16x8*)(&K_lds[jrow * 72 + seg]) = k0;
        *(u16x8*)(&K_lds[jrow * 72 + seg + 8]) = k1;
#pragma unroll
        for (int c = 0; c < 8; c++) V_lds[(seg + c) * 72 + jrow] = v0[c];
#pragma unroll
        for (int c = 0; c < 8; c++) V_lds[(seg + 8 + c) * 72 + jrow] = v1[c];
        __syncthreads();

        u16x8 nk0 = k0, nk1 = k1, nv0 = v0, nv1 = v1;
        if (t < 16) {
            const unsigned short* src = (t < 15)
                ? kvg + (size_t)((bm << 10) + ((t + 1) << 6) + jrow) * 2048 + (h << 6)
                : lkvg + (size_t)jrow * lstride + (h << 6);
            nk0 = *(const u16x8*)(src + seg);
            nk1 = *(const u16x8*)(src + seg + 8);
            nv0 = *(const u16x8*)(src + 1024 + seg);
            nv1 = *(const u16x8*)(src + 1024 + seg + 8);
        }

        f32x4 s[4] = {};
#pragma unroll
        for (int jt = 0; jt < 4; jt++) {
#pragma unroll
            for (int kk = 0; kk < 2; kk++) {
                bf16x8 kf = *(const bf16x8*)(&K_lds[(size_t)((jt << 4) + lr) * 72 + (kk << 5) + (lg << 3)]);
                s[jt] = __builtin_amdgcn_mfma_f32_16x16x32_bf16(qf[kk], kf, s[jt], 0, 0, 0);
            }
        }
#pragma unroll
        for (int r = 0; r < 4; r++) {
            float mx = fmaxf(fmaxf(s[0][r], s[1][r]), fmaxf(s[2][r], s[3][r]));
            mx = fmaxf(mx, __shfl_xor(mx, 1));
            mx = fmaxf(mx, __shfl_xor(mx, 2));
            mx = fmaxf(mx, __shfl_xor(mx, 4));
            mx = fmaxf(mx, __shfl_xor(mx, 8));
            float nm = fmaxf(m_run[r], mx);
            float fct = __expf(m_run[r] - nm);
            m_run[r] = nm;
            float p0 = __expf(s[0][r] - nm);
            float p1 = __expf(s[1][r] - nm);
            float p2 = __expf(s[2][r] - nm);
            float p3 = __expf(s[3][r] - nm);
            float sum = p0 + p1 + p2 + p3;
            sum += __shfl_xor(sum, 1);
            sum += __shfl_xor(sum, 2);
            sum += __shfl_xor(sum, 4);
            sum += __shfl_xor(sum, 8);
            l_run[r] = l_run[r] * fct + sum;
#pragma unroll
            for (int dt = 0; dt < 4; dt++) acc[dt][r] *= fct;
            int prow = ((lg << 2) + r) * 72;
            P_lds[w][prow + lr]      = f2bf(p0);
            P_lds[w][prow + 16 + lr] = f2bf(p1);
            P_lds[w][prow + 32 + lr] = f2bf(p2);
            P_lds[w][prow + 48 + lr] = f2bf(p3);
        }
#pragma unroll
        for (int jkk = 0; jkk < 2; jkk++) {
            bf16x8 pf = *(const bf16x8*)(&P_lds[w][(size_t)lr * 72 + (jkk << 5) + (lg << 3)]);
#pragma unroll
            for (int dt = 0; dt < 4; dt++) {
                bf16x8 vf = *(const bf16x8*)(&V_lds[(size_t)((dt << 4) + lr) * 72 + (jkk << 5) + (lg << 3)]);
                acc[dt] = __builtin_amdgcn_mfma_f32_16x16x32_bf16(pf, vf, acc[dt], 0, 0, 0);
            }
        }
        __syncthreads();
        k0 = nk0; k1 = nk1; v0 = nv0; v1 = nv1;
    }
#pragma unroll
    for (int dt = 0; dt < 4; dt++) {
#pragma unroll
        for (int r = 0; r < 4; r++) {
            int i = (w << 4) + (lg << 2) + r;
            float v = acc[dt][r] / l_run[r];
            og[(size_t)((bm << 6) + i) * 1024 + (h << 6) + (dt << 4) + lr] = f2bf(v);
        }
    }
}

extern "C" void kernel_launch(void* const* d_in, const int* in_sizes, int n_in,
                              void* d_out, int out_size, void* d_ws, size_t ws_size,
                              hipStream_t stream) {
    const float* x       = (const float*)d_in[0];
    const float* latents = (const float*)d_in[1];
    const float* Wq      = (const float*)d_in[2];
    const float* Wkv     = (const float*)d_in[3];
    const float* Wout    = (const float*)d_in[4];
    const float* bout    = (const float*)d_in[5];
    char* ws = (char*)d_ws;
    unsigned short* xb    = (unsigned short*)(ws);                 // 64 MiB  [32768][1024]
    unsigned short* kvb   = (unsigned short*)(ws + 67108864);      // 128 MiB [32768][2048]
    unsigned short* wqkvt = (unsigned short*)(ws + 201326592);     // 6 MiB   [3072][1024] (Wq^T | Wkv^T)
    unsigned short* wkvt  = wqkvt + 1024 * 1024;                   //         rows 1024..3071
    unsigned short* woutt = (unsigned short*)(ws + 207618048);     // 2 MiB   [1024][1024]
    unsigned short* latb  = (unsigned short*)(ws + 209715200);     // 128 KiB [64][1024]
    unsigned short* qlkvb = (unsigned short*)(ws + 209846272);     // 384 KiB [64][3072] (q | lk | lv)
    unsigned short* attnb = (unsigned short*)(ws + 210239488);     // 4 MiB   [2048][1024]

    cvt_kernel<<<2048, 256, 0, stream>>>(x, xb, 33554432 / 4);
    cvt_kernel<<<64, 256, 0, stream>>>(latents, latb, 65536 / 4);
    dim3 tb(32, 8);
    transpose_cvt<<<dim3(32, 32), tb, 0, stream>>>(Wq, wqkvt, 1024, 1024);
    transpose_cvt<<<dim3(64, 32), tb, 0, stream>>>(Wkv, wkvt, 1024, 2048);
    transpose_cvt<<<dim3(32, 32), tb, 0, stream>>>(Wout, woutt, 1024, 1024);
    // [q | lkv] = latents @ [Wq | Wkv]; q-part (cols<1024) scaled by dh^-0.5
    gemm128p<<<24, 256, 0, stream>>>(latb, wqkvt, qlkvb, nullptr, 64, 3072, 1024, 0.125f, 1024, 0);
    // kv = x @ Wkv  (dominant GEMM): 256x256 tiles, A-direct-to-reg
    gemm256<<<1024, 512, 0, stream>>>(xb, wkvt, kvb, 32768, 2048, 1024);
    // fused attention
    attn_kernel<<<512, 256, 0, stream>>>(qlkvb, 3072, kvb, qlkvb + 1024, 3072, attnb);
    // out = attnout @ Wout + bout (fp32 out)
    gemm128p<<<128, 256, 0, stream>>>(attnb, woutt, (void*)d_out, bout, 2048, 1024, 1024, 1.0f, 0, 1);
}

// Round 7
// 260.985 us; speedup vs baseline: 3.7326x; 1.6963x over previous
//
#include <hip/hip_runtime.h>
#include <cstdint>

typedef __attribute__((ext_vector_type(8))) __bf16 bf16x8;
typedef __attribute__((ext_vector_type(4))) float f32x4;
typedef __attribute__((ext_vector_type(8))) unsigned short u16x8;
typedef __attribute__((ext_vector_type(4))) unsigned short u16x4;

__device__ __forceinline__ unsigned short f2bf(float f) {
    union { float f; unsigned u; } v; v.f = f;
    unsigned u = v.u;
    return (unsigned short)((u + 0x7FFFu + ((u >> 16) & 1u)) >> 16);
}

__device__ __forceinline__ void gload_lds16(const void* g, void* l) {
    auto gp = reinterpret_cast<__attribute__((address_space(1))) unsigned*>(
        reinterpret_cast<uintptr_t>(g));
    auto lp = reinterpret_cast<__attribute__((address_space(3))) unsigned*>(
        reinterpret_cast<uintptr_t>(l));
    __builtin_amdgcn_global_load_lds(gp, lp, 16, 0, 0);
}

// ---------------- fp32 -> bf16 cast ----------------
__global__ __launch_bounds__(256) void cvt_kernel(const float* __restrict__ in,
                                                  unsigned short* __restrict__ out, int n4) {
    int idx = blockIdx.x * 256 + threadIdx.x;
    int stride = gridDim.x * 256;
    for (int i = idx; i < n4; i += stride) {
        float4 v = ((const float4*)in)[i];
        u16x4 o;
        o.x = f2bf(v.x); o.y = f2bf(v.y); o.z = f2bf(v.z); o.w = f2bf(v.w);
        ((u16x4*)out)[i] = o;
    }
}

// ---------------- fp32 [R][C] -> bf16 [C][R] ----------------
__global__ __launch_bounds__(256) void transpose_cvt(const float* __restrict__ in,
                                                     unsigned short* __restrict__ out,
                                                     int R, int C) {
    __shared__ float t[32][33];
    int c0 = blockIdx.x * 32, r0 = blockIdx.y * 32;
    int tx = threadIdx.x, ty = threadIdx.y;
    for (int i = ty; i < 32; i += 8)
        t[i][tx] = in[(size_t)(r0 + i) * C + c0 + tx];
    __syncthreads();
    for (int i = ty; i < 32; i += 8)
        out[(size_t)(c0 + i) * R + r0 + tx] = f2bf(t[tx][i]);
}

// ---------------- pipelined 128x128 bf16 GEMM (triple-buffer, counted vmcnt) ----
__global__ __launch_bounds__(256) void gemm128p(const unsigned short* __restrict__ A,
                                                const unsigned short* __restrict__ Bt,
                                                void* __restrict__ C,
                                                const float* __restrict__ bias,
                                                int M, int N, int K, float scale, int split,
                                                int c_f32) {
    __shared__ unsigned short lds[3][2][4096];  // 48 KiB
    int ntx = N >> 7;
    int nwg = gridDim.x, bid = blockIdx.x, swz = bid;
    if ((nwg & 7) == 0) { int cpx = nwg >> 3; swz = (bid & 7) * cpx + (bid >> 3); }
    int m0 = (swz / ntx) << 7, n0 = (swz % ntx) << 7;
    int tid = threadIdx.x, lane = tid & 63, w = tid >> 6;
    int wm = w >> 1, wn = w & 1;
    int lr = lane & 15, lg = lane >> 4;
    int gq = lg ^ ((lr >> 1) & 3);
    int nkt = K >> 5;

    int arow = tid >> 2;
    int sgl = (tid & 3) ^ ((arow >> 1) & 3);
    int ra0 = m0 + arow;      if (ra0 > M - 1) ra0 = M - 1;
    int ra1 = m0 + 64 + arow; if (ra1 > M - 1) ra1 = M - 1;
    const unsigned short* a0 = A + (size_t)ra0 * K + (sgl << 3);
    const unsigned short* a1 = A + (size_t)ra1 * K + (sgl << 3);
    const unsigned short* b0 = Bt + (size_t)(n0 + arow) * K + (sgl << 3);
    const unsigned short* b1 = Bt + (size_t)(n0 + 64 + arow) * K + (sgl << 3);

    f32x4 acc[4][4] = {};

#define ST_A128(bi, kt) do { \
        gload_lds16(a0 + ((kt) << 5), &lds[bi][0][w << 9]); \
        gload_lds16(a1 + ((kt) << 5), &lds[bi][0][2048 + (w << 9)]); } while (0)
#define ST_B128(bi, kt) do { \
        gload_lds16(b0 + ((kt) << 5), &lds[bi][1][w << 9]); \
        gload_lds16(b1 + ((kt) << 5), &lds[bi][1][2048 + (w << 9)]); } while (0)

    ST_A128(0, 0); ST_B128(0, 0);
    ST_A128(1, 1); ST_B128(1, 1);

    int buf = 0;
    for (int t = 0; t < nkt; ++t) {
        asm volatile("s_waitcnt vmcnt(4) lgkmcnt(0)" ::: "memory");
        __builtin_amdgcn_sched_barrier(0);
        __builtin_amdgcn_s_barrier();
        __builtin_amdgcn_sched_barrier(0);
        int st = t + 2; if (st >= nkt) st = nkt - 1;
        int sbuf = buf + 2; if (sbuf >= 3) sbuf -= 3;
        ST_A128(sbuf, st);
        ST_B128(sbuf, st);
        const unsigned short* pa = &lds[buf][0][((wm << 6) + lr) * 32 + (gq << 3)];
        const unsigned short* pb = &lds[buf][1][((wn << 6) + lr) * 32 + (gq << 3)];
        bf16x8 af[4], bfr[4];
#pragma unroll
        for (int nt = 0; nt < 4; nt++) bfr[nt] = *(const bf16x8*)(pb + nt * 512);
#pragma unroll
        for (int mt = 0; mt < 4; mt++) af[mt] = *(const bf16x8*)(pa + mt * 512);
        __builtin_amdgcn_s_setprio(1);
#pragma unroll
        for (int mt = 0; mt < 4; mt++)
#pragma unroll
            for (int nt = 0; nt < 4; nt++)
                acc[mt][nt] = __builtin_amdgcn_mfma_f32_16x16x32_bf16(af[mt], bfr[nt], acc[mt][nt], 0, 0, 0);
        __builtin_amdgcn_s_setprio(0);
        buf++; if (buf == 3) buf = 0;
    }
#undef ST_A128
#undef ST_B128

#pragma unroll
    for (int mt = 0; mt < 4; mt++) {
#pragma unroll
        for (int nt = 0; nt < 4; nt++) {
            int col = n0 + (wn << 6) + (nt << 4) + lr;
            float sc = (col < split) ? scale : 1.0f;
            float bv = bias ? bias[col] : 0.0f;
#pragma unroll
            for (int r = 0; r < 4; r++) {
                int row = m0 + (wm << 6) + (mt << 4) + (lg << 2) + r;
                if (row < M) {
                    float v = acc[mt][nt][r] * sc + bv;
                    if (c_f32) ((float*)C)[(size_t)row * N + col] = v;
                    else       ((unsigned short*)C)[(size_t)row * N + col] = f2bf(v);
                }
            }
        }
    }
}

// ---------------- large bf16 GEMM: 256x256, BK=64, 8-phase m201-style schedule ----------------
// dbuf=2 (128 KiB LDS), 8 waves (2m x 4n), per-wave 128x64, acc[8][4].
// Per K-tile: 4 phases x {ds_read frags; [stage]; lgkmcnt(0); setprio MFMA x16}.
// One vmcnt(4) per K-tile (P0: after issuing A(t+1), drains A(t)+B(t) exactly).
// Two barriers per K-tile: P0 pre-read (tile t published), P3 post-lgkmcnt (reads published
// before next iter's stage overwrites buf[t&1]).
// Swizzle: 8 granules(16B)/row, phys g' = g ^ (row&7); inverse-swizzled global source.
// Requires M%256==0, N%256==0, K%64==0, K>=128.
__global__ __launch_bounds__(512, 2) void gemm256(const unsigned short* __restrict__ A,
                                                  const unsigned short* __restrict__ Bt,
                                                  unsigned short* __restrict__ C,
                                                  int M, int N, int K) {
    __shared__ unsigned short lds[2][32768];  // [buf][A:0..16383 | B:16384..32767], 128 KiB
    int nkt = K >> 6;
    int ntx = N >> 8;
    int nwg = gridDim.x, bid = blockIdx.x, swz = bid;
    if ((nwg & 7) == 0) { int cpx = nwg >> 3; swz = (bid & 7) * cpx + (bid >> 3); }
    int m0 = (swz / ntx) << 8, n0 = (swz % ntx) << 8;
    int tid = threadIdx.x, lane = tid & 63, w = tid >> 6;
    int wm = w >> 2, wn = w & 3;
    int lr = lane & 15, lg = lane >> 4;

    // staging: load j covers rows j*64 + w*8 + (lane>>3), phys granule lane&7,
    // global (inverse-swizzled) granule (lane&7) ^ (lane>>3)   [row&7 == lane>>3]
    int srow = lane >> 3;
    int sg = (lane & 7) ^ srow;
    const unsigned short* aS = A + (size_t)(m0 + (w << 3) + srow) * K + (sg << 3);
    const unsigned short* bS = Bt + (size_t)(n0 + (w << 3) + srow) * K + (sg << 3);
    size_t rs64 = (size_t)64 * K;

    // read offsets (elements): A row = wm*128 + mt*16 + lr; B row = wn*64 + nt*16 + lr
    // phys granule for k-slice ks: ((ks*4 + lg) ^ (lr&7))
    int baseA = (wm << 13) + lr * 64;
    int baseB = 16384 + (wn << 12) + lr * 64;
    int kg0 = (((0 << 2) + lg) ^ (lr & 7)) << 3;
    int kg1 = (((1 << 2) + lg) ^ (lr & 7)) << 3;

    f32x4 acc[8][4] = {};

#define ST_A(bi, kt) do { \
        gload_lds16(aS + ((size_t)(kt) << 6),          &lds[bi][(w << 9)]); \
        gload_lds16(aS + rs64 + ((size_t)(kt) << 6),   &lds[bi][4096 + (w << 9)]); \
        gload_lds16(aS + 2*rs64 + ((size_t)(kt) << 6), &lds[bi][8192 + (w << 9)]); \
        gload_lds16(aS + 3*rs64 + ((size_t)(kt) << 6), &lds[bi][12288 + (w << 9)]); } while (0)
#define ST_B(bi, kt) do { \
        gload_lds16(bS + ((size_t)(kt) << 6),          &lds[bi][16384 + (w << 9)]); \
        gload_lds16(bS + rs64 + ((size_t)(kt) << 6),   &lds[bi][20480 + (w << 9)]); \
        gload_lds16(bS + 2*rs64 + ((size_t)(kt) << 6), &lds[bi][24576 + (w << 9)]); \
        gload_lds16(bS + 3*rs64 + ((size_t)(kt) << 6), &lds[bi][28672 + (w << 9)]); } while (0)

    // prologue: tile 0 fully staged (8 loads)
    ST_A(0, 0);
    ST_B(0, 0);

    for (int t = 0; t < nkt; ++t) {
        int cur = t & 1, nxt = cur ^ 1;
        int st = t + 1; if (st >= nkt) st = nkt - 1;
        const unsigned short* L = &lds[cur][0];
        bf16x8 af[4], bfr[4];

        // ---- P0: stage A(t+1); vmcnt(4) publishes tile t; reads ks0 m0-3 + B ks0 ----
        ST_A(nxt, st);
        __builtin_amdgcn_sched_barrier(0);
        asm volatile("s_waitcnt vmcnt(4)" ::: "memory");
        __builtin_amdgcn_sched_barrier(0);
        __builtin_amdgcn_s_barrier();
        __builtin_amdgcn_sched_barrier(0);
#pragma unroll
        for (int nt = 0; nt < 4; nt++) bfr[nt] = *(const bf16x8*)(L + baseB + nt * 1024 + kg0);
#pragma unroll
        for (int i = 0; i < 4; i++) af[i] = *(const bf16x8*)(L + baseA + i * 1024 + kg0);
        asm volatile("s_waitcnt lgkmcnt(0)" ::: "memory");
        __builtin_amdgcn_sched_barrier(0);
        __builtin_amdgcn_s_setprio(1);
#pragma unroll
        for (int i = 0; i < 4; i++)
#pragma unroll
            for (int nt = 0; nt < 4; nt++)
                acc[i][nt] = __builtin_amdgcn_mfma_f32_16x16x32_bf16(af[i], bfr[nt], acc[i][nt], 0, 0, 0);
        __builtin_amdgcn_s_setprio(0);

        // ---- P1: stage B(t+1); reads ks0 m4-7 ----
        ST_B(nxt, st);
#pragma unroll
        for (int i = 0; i < 4; i++) af[i] = *(const bf16x8*)(L + baseA + (i + 4) * 1024 + kg0);
        asm volatile("s_waitcnt lgkmcnt(0)" ::: "memory");
        __builtin_amdgcn_sched_barrier(0);
        __builtin_amdgcn_s_setprio(1);
#pragma unroll
        for (int i = 0; i < 4; i++)
#pragma unroll
            for (int nt = 0; nt < 4; nt++)
                acc[i + 4][nt] = __builtin_amdgcn_mfma_f32_16x16x32_bf16(af[i], bfr[nt], acc[i + 4][nt], 0, 0, 0);
        __builtin_amdgcn_s_setprio(0);

        // ---- P2: reads ks1 m0-3 + B ks1 ----
#pragma unroll
        for (int nt = 0; nt < 4; nt++) bfr[nt] = *(const bf16x8*)(L + baseB + nt * 1024 + kg1);
#pragma unroll
        for (int i = 0; i < 4; i++) af[i] = *(const bf16x8*)(L + baseA + i * 1024 + kg1);
        asm volatile("s_waitcnt lgkmcnt(0)" ::: "memory");
        __builtin_amdgcn_sched_barrier(0);
        __builtin_amdgcn_s_setprio(1);
#pragma unroll
        for (int i = 0; i < 4; i++)
#pragma unroll
            for (int nt = 0; nt < 4; nt++)
                acc[i][nt] = __builtin_amdgcn_mfma_f32_16x16x32_bf16(af[i], bfr[nt], acc[i][nt], 0, 0, 0);
        __builtin_amdgcn_s_setprio(0);

        // ---- P3: reads ks1 m4-7; closing barrier after lgkmcnt publishes read-completion ----
#pragma unroll
        for (int i = 0; i < 4; i++) af[i] = *(const bf16x8*)(L + baseA + (i + 4) * 1024 + kg1);
        asm volatile("s_waitcnt lgkmcnt(0)" ::: "memory");
        __builtin_amdgcn_sched_barrier(0);
        __builtin_amdgcn_s_barrier();
        __builtin_amdgcn_sched_barrier(0);
        __builtin_amdgcn_s_setprio(1);
#pragma unroll
        for (int i = 0; i < 4; i++)
#pragma unroll
            for (int nt = 0; nt < 4; nt++)
                acc[i + 4][nt] = __builtin_amdgcn_mfma_f32_16x16x32_bf16(af[i], bfr[nt], acc[i + 4][nt], 0, 0, 0);
        __builtin_amdgcn_s_setprio(0);
    }
#undef ST_A
#undef ST_B

#pragma unroll
    for (int mt = 0; mt < 8; mt++) {
#pragma unroll
        for (int nt = 0; nt < 4; nt++) {
            int col = n0 + (wn << 6) + (nt << 4) + lr;
            size_t rbase = (size_t)(m0 + (wm << 7) + (mt << 4) + (lg << 2));
#pragma unroll
            for (int r = 0; r < 4; r++)
                C[(rbase + r) * N + col] = f2bf(acc[mt][nt][r]);
        }
    }
}

// ---------------- fused flash attention over 1088 keys (1024 media + 64 latent) ----------------
__global__ __launch_bounds__(256) void attn_kernel(const unsigned short* __restrict__ qg, int qstride,
                                                   const unsigned short* __restrict__ kvg,
                                                   const unsigned short* __restrict__ lkvg, int lstride,
                                                   unsigned short* __restrict__ og) {
    __shared__ unsigned short K_lds[64 * 72];
    __shared__ unsigned short V_lds[64 * 72];
    __shared__ unsigned short P_lds[4][16 * 72];
    int bm = blockIdx.x >> 4, h = blockIdx.x & 15;
    int tid = threadIdx.x, lane = tid & 63, w = tid >> 6;
    int lr = lane & 15, lg = lane >> 4;

    bf16x8 qf[2];
#pragma unroll
    for (int kk = 0; kk < 2; kk++)
        qf[kk] = *(const bf16x8*)(qg + (size_t)((w << 4) + lr) * qstride + (h << 6) + (kk << 5) + (lg << 3));

    f32x4 acc[4] = {};
    float m_run[4], l_run[4];
#pragma unroll
    for (int r = 0; r < 4; r++) { m_run[r] = -1e30f; l_run[r] = 0.0f; }

    int jrow = tid >> 2;
    int seg = (tid & 3) << 4;

    const unsigned short* s0 = kvg + (size_t)((bm << 10) + jrow) * 2048 + (h << 6);
    u16x8 k0 = *(const u16x8*)(s0 + seg);
    u16x8 k1 = *(const u16x8*)(s0 + seg + 8);
    u16x8 v0 = *(const u16x8*)(s0 + 1024 + seg);
    u16x8 v1 = *(const u16x8*)(s0 + 1024 + seg + 8);

    for (int t = 0; t < 17; t++) {
        *(u16x8*)(&K_lds[jrow * 72 + seg]) = k0;
        *(u16x8*)(&K_lds[jrow * 72 + seg + 8]) = k1;
#pragma unroll
        for (int c = 0; c < 8; c++) V_lds[(seg + c) * 72 + jrow] = v0[c];
#pragma unroll
        for (int c = 0; c < 8; c++) V_lds[(seg + 8 + c) * 72 + jrow] = v1[c];
        __syncthreads();

        u16x8 nk0 = k0, nk1 = k1, nv0 = v0, nv1 = v1;
        if (t < 16) {
            const unsigned short* src = (t < 15)
                ? kvg + (size_t)((bm << 10) + ((t + 1) << 6) + jrow) * 2048 + (h << 6)
                : lkvg + (size_t)jrow * lstride + (h << 6);
            nk0 = *(const u16x8*)(src + seg);
            nk1 = *(const u16x8*)(src + seg + 8);
            nv0 = *(const u16x8*)(src + 1024 + seg);
            nv1 = *(const u16x8*)(src + 1024 + seg + 8);
        }

        f32x4 s[4] = {};
#pragma unroll
        for (int jt = 0; jt < 4; jt++) {
#pragma unroll
            for (int kk = 0; kk < 2; kk++) {
                bf16x8 kf = *(const bf16x8*)(&K_lds[(size_t)((jt << 4) + lr) * 72 + (kk << 5) + (lg << 3)]);
                s[jt] = __builtin_amdgcn_mfma_f32_16x16x32_bf16(qf[kk], kf, s[jt], 0, 0, 0);
            }
        }
#pragma unroll
        for (int r = 0; r < 4; r++) {
            float mx = fmaxf(fmaxf(s[0][r], s[1][r]), fmaxf(s[2][r], s[3][r]));
            mx = fmaxf(mx, __shfl_xor(mx, 1));
            mx = fmaxf(mx, __shfl_xor(mx, 2));
            mx = fmaxf(mx, __shfl_xor(mx, 4));
            mx = fmaxf(mx, __shfl_xor(mx, 8));
            float nm = fmaxf(m_run[r], mx);
            float fct = __expf(m_run[r] - nm);
            m_run[r] = nm;
            float p0 = __expf(s[0][r] - nm);
            float p1 = __expf(s[1][r] - nm);
            float p2 = __expf(s[2][r] - nm);
            float p3 = __expf(s[3][r] - nm);
            float sum = p0 + p1 + p2 + p3;
            sum += __shfl_xor(sum, 1);
            sum += __shfl_xor(sum, 2);
            sum += __shfl_xor(sum, 4);
            sum += __shfl_xor(sum, 8);
            l_run[r] = l_run[r] * fct + sum;
#pragma unroll
            for (int dt = 0; dt < 4; dt++) acc[dt][r] *= fct;
            int prow = ((lg << 2) + r) * 72;
            P_lds[w][prow + lr]      = f2bf(p0);
            P_lds[w][prow + 16 + lr] = f2bf(p1);
            P_lds[w][prow + 32 + lr] = f2bf(p2);
            P_lds[w][prow + 48 + lr] = f2bf(p3);
        }
#pragma unroll
        for (int jkk = 0; jkk < 2; jkk++) {
            bf16x8 pf = *(const bf16x8*)(&P_lds[w][(size_t)lr * 72 + (jkk << 5) + (lg << 3)]);
#pragma unroll
            for (int dt = 0; dt < 4; dt++) {
                bf16x8 vf = *(const bf16x8*)(&V_lds[(size_t)((dt << 4) + lr) * 72 + (jkk << 5) + (lg << 3)]);
                acc[dt] = __builtin_amdgcn_mfma_f32_16x16x32_bf16(pf, vf, acc[dt], 0, 0, 0);
            }
        }
        __syncthreads();
        k0 = nk0; k1 = nk1; v0 = nv0; v1 = nv1;
    }
#pragma unroll
    for (int dt = 0; dt < 4; dt++) {
#pragma unroll
        for (int r = 0; r < 4; r++) {
            int i = (w << 4) + (lg << 2) + r;
            float v = acc[dt][r] / l_run[r];
            og[(size_t)((bm << 6) + i) * 1024 + (h << 6) + (dt << 4) + lr] = f2bf(v);
        }
    }
}

extern "C" void kernel_launch(void* const* d_in, const int* in_sizes, int n_in,
                              void* d_out, int out_size, void* d_ws, size_t ws_size,
                              hipStream_t stream) {
    const float* x       = (const float*)d_in[0];
    const float* latents = (const float*)d_in[1];
    const float* Wq      = (const float*)d_in[2];
    const float* Wkv     = (const float*)d_in[3];
    const float* Wout    = (const float*)d_in[4];
    const float* bout    = (const float*)d_in[5];
    char* ws = (char*)d_ws;
    unsigned short* xb    = (unsigned short*)(ws);                 // 64 MiB  [32768][1024]
    unsigned short* kvb   = (unsigned short*)(ws + 67108864);      // 128 MiB [32768][2048]
    unsigned short* wqkvt = (unsigned short*)(ws + 201326592);     // 6 MiB   [3072][1024] (Wq^T | Wkv^T)
    unsigned short* wkvt  = wqkvt + 1024 * 1024;                   //         rows 1024..3071
    unsigned short* woutt = (unsigned short*)(ws + 207618048);     // 2 MiB   [1024][1024]
    unsigned short* latb  = (unsigned short*)(ws + 209715200);     // 128 KiB [64][1024]
    unsigned short* qlkvb = (unsigned short*)(ws + 209846272);     // 384 KiB [64][3072] (q | lk | lv)
    unsigned short* attnb = (unsigned short*)(ws + 210239488);     // 4 MiB   [2048][1024]

    cvt_kernel<<<2048, 256, 0, stream>>>(x, xb, 33554432 / 4);
    cvt_kernel<<<64, 256, 0, stream>>>(latents, latb, 65536 / 4);
    dim3 tb(32, 8);
    transpose_cvt<<<dim3(32, 32), tb, 0, stream>>>(Wq, wqkvt, 1024, 1024);
    transpose_cvt<<<dim3(64, 32), tb, 0, stream>>>(Wkv, wkvt, 1024, 2048);
    transpose_cvt<<<dim3(32, 32), tb, 0, stream>>>(Wout, woutt, 1024, 1024);
    // [q | lkv] = latents @ [Wq | Wkv]; q-part (cols<1024) scaled by dh^-0.5
    gemm128p<<<24, 256, 0, stream>>>(latb, wqkvt, qlkvb, nullptr, 64, 3072, 1024, 0.125f, 1024, 0);
    // kv = x @ Wkv  (dominant GEMM): 256x256, BK=64, 8-phase schedule
    gemm256<<<1024, 512, 0, stream>>>(xb, wkvt, kvb, 32768, 2048, 1024);
    // fused attention
    attn_kernel<<<512, 256, 0, stream>>>(qlkvb, 3072, kvb, qlkvb + 1024, 3072, attnb);
    // out = attnout @ Wout + bout (fp32 out)
    gemm128p<<<128, 256, 0, stream>>>(attnb, woutt, (void*)d_out, bout, 2048, 1024, 1024, 1.0f, 0, 1);
}